// Round 18
// baseline (32.896 us; speedup 1.0000x reference)
//
#include <hip/hip_runtime.h>
#include <hip/hip_bf16.h>

#define UNITS 64
#define IFEAT 256
#define OFEAT 256

typedef __attribute__((ext_vector_type(8))) short v8s;   // 8 bf16 (4 VGPRs)
typedef __attribute__((ext_vector_type(4))) float v4f;   // MFMA acc / global f32x4

// pack 2 floats -> u32 of 2 bf16 (RNE) — compiler emits v_cvt_pk_bf16_f32
static __device__ __forceinline__ unsigned int pk2(float a, float b) {
    union { __hip_bfloat162 h; unsigned int u; } c;
    c.h = __float22bfloat162_rn(float2{a, b});
    return c.u;
}
static __device__ __forceinline__ v8s pk8(const float* r) {
    union { uint4 u4; v8s s8; } cv;
    cv.u4.x = pk2(r[0], r[1]);
    cv.u4.y = pk2(r[2], r[3]);
    cv.u4.z = pk2(r[4], r[5]);
    cv.u4.w = pk2(r[6], r[7]);
    return cv.s8;
}

static __device__ __forceinline__ float sigmoid_f(float x) {
    return 1.0f / (1.0f + __expf(-x));
}
static __device__ __forceinline__ float tanh_f(float x) {
    float ax = fabsf(x);
    float e = __expf(-2.0f * ax);
    float t = (1.0f - e) / (1.0f + e);
    return copysignf(t, x);
}

// ---------------------------------------------------------------------------
// Fused GRU = R17 (best, 31.8us: barrier-free, B-in-reg, 2-stage f32->bf16
// operand pipeline, 8 waves x wave-tile 128x16) with ONE change:
// INTERLEAVED step order x0,h0,x1,h1,... instead of 8 x-steps then 8
// h-steps. R17's h-phase issued 24 loads/step with only 3 MFMAs of cover
// (8 exposed latency chains); interleaving gives every h-load burst a full
// x-step (24 MFMA + 8 ds_read + 24 load-issues) of cover. Zero register
// cost: buffer parity == step type (rbFa/bfQa = x, rbFb/bfQb = h), 2-step
// issue distance preserved.
// Grid 256 = 64u x 2mb x 2nb (XCD-swizzled), 512 thr, 1 block/CU.
// Budget: acc 96 + acch 12 + rbF 48 + bfQ 24 + frags/addr ~50 ≈ 230 of 256
// (2 waves/SIMD). WRITE_SIZE is the spill sentinel.
// ---------------------------------------------------------------------------
__global__ __launch_bounds__(512, 1) void gru_fused(
    const float* __restrict__ x,
    const float* __restrict__ wir,
    const float* __restrict__ wiz,
    const float* __restrict__ win,
    const float* __restrict__ whr,
    const float* __restrict__ whz,
    const float* __restrict__ whn,
    const float* __restrict__ hinit,
    float* __restrict__ out) {
    __shared__ unsigned short As[32][128][8];        // [kq][row'][j]   64 KB
    __shared__ unsigned short Ht[32][8];             // h broadcast    512 B

    const int bid = blockIdx.x;
    // XCD swizzle: xcd = bid&7 owns units [xcd*8, xcd*8+8); 4 blocks/unit.
    const int idx = bid >> 3;                  // 0..31 within XCD
    const int u   = (bid & 7) * 8 + (idx >> 2);
    const int rem = idx & 3;
    const int b0  = (rem >> 1) * 128;          // batch tile 0..1
    const int o0  = (rem & 1) * 128;           // out-feature tile 0..1

    const int t    = threadIdx.x;
    const int lane = t & 63;
    const int wv   = t >> 6;                   // 8 waves = 8 col-slices
    const int lg   = lane >> 4;                // k-group 0..3
    const int lr   = lane & 15;

    const float* WX[3] = {wir, wiz, win};
    const float* WH[3] = {whr, whz, whn};

    // per-thread B base offset (col = o0 + wv*16 + lr owned by this lane)
    const size_t bcolofs = (size_t)u * (IFEAT * OFEAT) + o0 + wv * 16 + lr;

    float rbFa[3][8], rbFb[3][8];              // f32 dbuf: a = x-type, b = h-type
    v8s bfQa[3], bfQb[3];                      // bf16 queue: a = x-type, b = h

    // step s: type = s&1 (0 = W_i, 1 = W_h), k-phase p = s>>1
#define LOADB(dst, s)                                                        \
    {                                                                        \
        const float* const* W = ((s) & 1) ? WH : WX;                         \
        const size_t boff = bcolofs + (size_t)(((s) >> 1) * 4 + lg) * 8 * OFEAT; \
        _Pragma("unroll")                                                    \
        for (int g = 0; g < 3; ++g) {                                        \
            const float* p = W[g] + boff;                                    \
            _Pragma("unroll")                                                \
            for (int j = 0; j < 8; ++j) dst[g][j] = p[j * OFEAT];            \
        }                                                                    \
    }
#define CVTQ(dq, sr)                                                         \
    {                                                                        \
        _Pragma("unroll")                                                    \
        for (int g = 0; g < 3; ++g) dq[g] = pk8(sr[g]);                      \
    }

    // ---- prologue: issue loads(0)=x,p0 and (1)=h,p0 first, then stage A+Ht
    LOADB(rbFa, 0);
    LOADB(rbFb, 1);
    {
        const int kqA = lane >> 1;             // lane owns k = lane*4..+3
        const int j0  = (lane & 1) * 4;
#pragma unroll
        for (int i = 0; i < 16; ++i) {
            const int row = wv * 16 + i;
            v4f q = *(const v4f*)(x + (size_t)(b0 + row) * (UNITS * IFEAT)
                                    + u * IFEAT + lane * 4);
            uint2 w;
            w.x = pk2(q[0], q[1]);
            w.y = pk2(q[2], q[3]);
            *(uint2*)&As[kqA][(row + kqA) & 127][j0] = w;
        }
    }
    if (t < 32) {
        const float* hp = hinit + u * IFEAT + t * 8;
        v4f q0 = *(const v4f*)hp;
        v4f q1 = *(const v4f*)(hp + 4);
        uint4 w;
        w.x = pk2(q0[0], q0[1]);
        w.y = pk2(q0[2], q0[3]);
        w.z = pk2(q1[0], q1[1]);
        w.w = pk2(q1[2], q1[3]);
        *(uint4*)&Ht[t][0] = w;
    }

    v4f acc[3][8];                             // [gate][mi] x-part
    v4f acch[3];                               // [gate]     h-part (bcast)
#pragma unroll
    for (int g = 0; g < 3; ++g) {
#pragma unroll
        for (int mi = 0; mi < 8; ++mi)
            acc[g][mi] = (v4f){0.f, 0.f, 0.f, 0.f};
        acch[g] = (v4f){0.f, 0.f, 0.f, 0.f};
    }

    __syncthreads();                           // the ONLY barrier
    CVTQ(bfQa, rbFa);                          // cvt step 0 (x, p0)

    // ---- K-loop: 16 interleaved steps x0,h0,x1,h1,...,x7,h7 -------------
#pragma unroll
    for (int s = 0; s < 16; ++s) {
        // 1) issue loads(s+2) (same type/buffer parity as s)
        if (s < 14) {
            if (s & 1) { LOADB(rbFb, s + 2); }
            else       { LOADB(rbFa, s + 2); }
        }

        // 2) MFMA(s) — operands converted at the end of step s-1
        const int kq = (s >> 1) * 4 + lg;
        if ((s & 1) == 0) {
            // x-step: 24 MFMAs + 8 ds_read_b128 (the heavy cover)
#pragma unroll
            for (int mi = 0; mi < 8; ++mi) {
                v8s a = *(const v8s*)&As[kq][((mi * 16 + lr) + kq) & 127][0];
#pragma unroll
                for (int g = 0; g < 3; ++g)
                    acc[g][mi] = __builtin_amdgcn_mfma_f32_16x16x32_bf16(
                        a, bfQa[g], acc[g][mi], 0, 0, 0);
            }
        } else {
            // h-step: broadcast A, 3 MFMAs (rides in the x-step gaps)
            v8s a0h = *(const v8s*)&Ht[kq][0];
#pragma unroll
            for (int g = 0; g < 3; ++g)
                acch[g] = __builtin_amdgcn_mfma_f32_16x16x32_bf16(
                    a0h, bfQb[g], acch[g], 0, 0, 0);
        }

        // 3) cvt(s+1): consumes the buffer loaded at step s-1
        if (s < 15) {
            if (s & 1) { CVTQ(bfQa, rbFa); }
            else       { CVTQ(bfQb, rbFb); }
        }
    }
#undef LOADB
#undef CVTQ

    // ---- epilogue: GRU combine ----
    // C layout: col = lane&15, row = (lane>>4)*4 + reg; acch rows identical
    const int o = o0 + wv * 16 + lr;
    const float h0v = hinit[u * OFEAT + o];
    const float hr = acch[0][0];
    const float hz = acch[1][0];
    const float hn = acch[2][0];
#pragma unroll
    for (int mi = 0; mi < 8; ++mi) {
#pragma unroll
        for (int jj = 0; jj < 4; ++jj) {
            const int row = b0 + mi * 16 + lg * 4 + jj;
            const float r = sigmoid_f(acc[0][mi][jj] + hr);
            const float z = sigmoid_f(acc[1][mi][jj] + hz);
            const float n = tanh_f(acc[2][mi][jj] + r * hn);
            out[(size_t)row * (UNITS * OFEAT) + u * OFEAT + o] =
                (1.0f - z) * n + z * h0v;
        }
    }
}

extern "C" void kernel_launch(void* const* d_in, const int* in_sizes, int n_in,
                              void* d_out, int out_size, void* d_ws, size_t ws_size,
                              hipStream_t stream) {
    const float* x     = (const float*)d_in[0];
    const float* w_ir  = (const float*)d_in[1];
    const float* w_iz  = (const float*)d_in[2];
    const float* w_in  = (const float*)d_in[3];
    const float* w_hr  = (const float*)d_in[4];
    const float* w_hz  = (const float*)d_in[5];
    const float* w_hn  = (const float*)d_in[6];
    const float* hinit = (const float*)d_in[7];
    float* out = (float*)d_out;

    gru_fused<<<dim3(256), dim3(512), 0, stream>>>(
        x, w_ir, w_iz, w_in, w_hr, w_hz, w_hn, hinit, out);
}